// Round 6
// baseline (218.227 us; speedup 1.0000x reference)
//
#include <hip/hip_runtime.h>

#define S_LEN 4096
#define BATCH 2
#define DIM 64
#define RAD 128
#define NPOS 257
#define KEXT 4416              // 4096 + 5*64 (rel rows padded)
#define QREL_STR 260
#define PSTR 72                // P LDS row stride in u16 (144B, 16B-aligned)
#define ETS 516                // etile row stride in f32

typedef short s16x8 __attribute__((ext_vector_type(8)));
typedef short s16x4 __attribute__((ext_vector_type(4)));
typedef float f32x4 __attribute__((ext_vector_type(4)));
typedef unsigned short u16;
typedef unsigned int u32;

__device__ __forceinline__ u16 f2bf(float f) {
  union { float f; u32 u; } v; v.f = f;
  u32 u = v.u;
  return (u16)((u + 0x7FFFu + ((u >> 16) & 1u)) >> 16);  // RNE
}

// Kb_ext[b][t][d]: t<4096 -> bf16(K); 4096<=t<4353 -> bf16(rel[t-4096]); else 0
__global__ void prep_k(const float* __restrict__ K, const float* __restrict__ rel,
                       u16* __restrict__ Kb) {
  int b = blockIdx.y;
  int t = blockIdx.x * 4 + (threadIdx.x >> 6);
  int d = threadIdx.x & 63;
  float v = 0.f;
  if (t < S_LEN) v = K[((size_t)b * S_LEN + t) * DIM + d];
  else if (t - S_LEN < NPOS) v = rel[(size_t)(t - S_LEN) * DIM + d];
  Kb[((size_t)b * KEXT + t) * DIM + d] = f2bf(v);
}

// Vt[b][d][t] = bf16(V[b][t][d])
__global__ void prep_v(const float* __restrict__ V, u16* __restrict__ Vt) {
  __shared__ float tile[64][65];
  int b = blockIdx.y;
  int t0 = blockIdx.x * 64;
  for (int i = threadIdx.x; i < 4096; i += 256) {
    int tl = i >> 6, d = i & 63;
    tile[tl][d] = V[((size_t)b * S_LEN + t0 + tl) * DIM + d];
  }
  __syncthreads();
  for (int i = threadIdx.x; i < 4096; i += 256) {
    int d = i >> 6, tl = i & 63;
    Vt[((size_t)b * DIM + d) * S_LEN + t0 + tl] = f2bf(tile[tl][d]);
  }
}

// ABLATION ROUND. MODE 0: real energy stores to d_out (canonical layout).
// MODE 1: no global energy stores — values read back from LDS and kept live
//         via asm sink (rule #17: prevents DCE of the whole compute chain).
// MODE 2: energy stored to a per-block LINEAR region (fill-like address
//         stream, same 134 MB volume).
// All other code (MFMA, softmax, LDS staging, barriers, Z path) identical.
template <int MODE>
__launch_bounds__(512, 4)
__global__ void attn_main(const float* __restrict__ Q,
                          const u16* __restrict__ Kb,
                          const u16* __restrict__ Vt,
                          float* __restrict__ energy,
                          float* __restrict__ Zout) {
  __shared__ float qrel[16 * QREL_STR];   // 16640 B; [q=l15][p]
  __shared__ u16 plds[8 * 16 * PSTR];     // 18432 B
  __shared__ float etile[16 * ETS];       // 33024 B; [q-row][col in tile]

  const int tid = threadIdx.x;
  const int lane = tid & 63;
  const int wid = tid >> 6;
  const int l15 = lane & 15, q4 = lane >> 4;
  const int l31 = lane & 31, h = lane >> 5;
  const int bx = blockIdx.x;
  const int b = bx >> 8;
  const int s0 = (bx & 255) * 16;

  const u16* KbB = Kb + (size_t)b * KEXT * DIM;
  const u16* VtB = Vt + (size_t)b * DIM * S_LEN;

  // ---- Q B-fragments (row s0+l15) ----
  s16x8 qfrag[2];
  {
    const float* qp = Q + ((size_t)b * S_LEN + s0 + l15) * DIM + q4 * 8;
#pragma unroll
    for (int ks = 0; ks < 2; ++ks) {
      f32x4 a = *reinterpret_cast<const f32x4*>(qp + ks * 32);
      f32x4 c = *reinterpret_cast<const f32x4*>(qp + ks * 32 + 4);
      s16x8 f;
#pragma unroll
      for (int j = 0; j < 4; ++j) { f[j] = (short)f2bf(a[j]); f[4 + j] = (short)f2bf(c[j]); }
      qfrag[ks] = f;
    }
  }

  const int koff_lane = l15 * DIM + q4 * 8;

  // ---- prologue: Q_rel[p][q] via mfma(rel, q) ----
  if (wid < 5) {
    f32x4 acc[4] = {};
    const u16* kp = KbB + (size_t)(S_LEN + wid * 64) * DIM + koff_lane;
#pragma unroll
    for (int ks = 0; ks < 2; ++ks)
#pragma unroll
      for (int nf = 0; nf < 4; ++nf) {
        s16x8 kf = *reinterpret_cast<const s16x8*>(kp + nf * 16 * DIM + ks * 32);
        acc[nf] = __builtin_amdgcn_mfma_f32_16x16x32_bf16(kf, qfrag[ks], acc[nf], 0, 0, 0);
      }
#pragma unroll
    for (int nf = 0; nf < 4; ++nf)
#pragma unroll
      for (int reg = 0; reg < 4; ++reg) {
        int p = wid * 64 + nf * 16 + q4 * 4 + reg;
        if (p < NPOS) qrel[l15 * QREL_STR + p] = acc[nf][reg];
      }
  }
  __syncthreads();

  // ---- main loop: 8 block-wide t-tiles of 512 ----
  const int qglob = s0 + l15;
  const int qoff = l15 * QREL_STR + RAD;
  u16* pw = plds + wid * 16 * PSTR;
  float* eb = etile + l15 * ETS + wid * 64;     // this wave's compute slice
  float* erow0 = energy + ((size_t)b * S_LEN + s0) * S_LEN;

  float mprev = -INFINITY, lsum = 0.f;
  f32x4 zacc[4] = {};

  for (int it = 0; it < 8; ++it) {
    const int t0 = it * 512 + wid * 64;

    f32x4 acc[4] = {};
    const u16* kp = KbB + (size_t)t0 * DIM + koff_lane;
#pragma unroll
    for (int ks = 0; ks < 2; ++ks)
#pragma unroll
      for (int nf = 0; nf < 4; ++nf) {
        s16x8 kf = *reinterpret_cast<const s16x8*>(kp + nf * 16 * DIM + ks * 32);
        acc[nf] = __builtin_amdgcn_mfma_f32_16x16x32_bf16(kf, qfrag[ks], acc[nf], 0, 0, 0);
      }

    // rel shift + scale; stage into block LDS tile; lane-local max
    float mloc = -INFINITY;
#pragma unroll
    for (int nf = 0; nf < 4; ++nf) {
      const int tb = t0 + nf * 16 + q4 * 4;
#pragma unroll
      for (int reg = 0; reg < 4; ++reg) {
        int p = tb + reg - qglob;
        p = (p < -RAD) ? -RAD : (p > RAD ? RAD : p);
        float e = (acc[nf][reg] + qrel[qoff + p]) * 0.125f;
        acc[nf][reg] = e;
        mloc = fmaxf(mloc, e);
      }
      *reinterpret_cast<f32x4*>(eb + nf * 16 + q4 * 4) = acc[nf];
    }

    mloc = fmaxf(mloc, __shfl_xor(mloc, 16));
    mloc = fmaxf(mloc, __shfl_xor(mloc, 32));
    const float mn = fmaxf(mprev, mloc);
    const float alpha = __expf(mprev - mn);
    mprev = mn;
    lsum *= alpha;
#pragma unroll
    for (int dn = 0; dn < 4; ++dn) zacc[dn] *= alpha;

    float rs = 0.f;
#pragma unroll
    for (int nf = 0; nf < 4; ++nf) {
      s16x4 p4;
#pragma unroll
      for (int reg = 0; reg < 4; ++reg) {
        float pv = __expf(acc[nf][reg] - mn);
        rs += pv;
        p4[reg] = (short)f2bf(pv);
      }
      *reinterpret_cast<s16x4*>(pw + l15 * PSTR + nf * 16 + q4 * 4) = p4;
    }
    rs += __shfl_xor(rs, 16);
    rs += __shfl_xor(rs, 32);
    lsum += rs;

    // PV: mfma(vf, pf) -> zacc[dn] holds Z[d=dn*16+q4*4+reg][q=l15]
#pragma unroll
    for (int ks = 0; ks < 2; ++ks) {
      s16x8 pf = *reinterpret_cast<const s16x8*>(pw + l15 * PSTR + ks * 32 + q4 * 8);
#pragma unroll
      for (int dn = 0; dn < 4; ++dn) {
        s16x8 vf = *reinterpret_cast<const s16x8*>(
            VtB + (size_t)(dn * 16 + l15) * S_LEN + t0 + ks * 32 + q4 * 8);
        zacc[dn] = __builtin_amdgcn_mfma_f32_16x16x32_bf16(vf, pf, zacc[dn], 0, 0, 0);
      }
    }

    // ---- store phase (the experimental arm) ----
    __syncthreads();
    {
      const int r = wid * 2 + h;
      const float* src = etile + r * ETS;
#pragma unroll
      for (int c = 0; c < 4; ++c) {
        f32x4 v = *reinterpret_cast<const f32x4*>(src + c * 128 + l31 * 4);
        if constexpr (MODE == 0) {
          __builtin_nontemporal_store(
              v, reinterpret_cast<f32x4*>(erow0 + (size_t)r * S_LEN + it * 512 + c * 128 + l31 * 4));
        } else if constexpr (MODE == 2) {
          float* dst = energy + (size_t)bx * 65536 + it * 8192 + r * 512 + c * 128 + l31 * 4;
          __builtin_nontemporal_store(v, reinterpret_cast<f32x4*>(dst));
        } else {
          asm volatile("" ::"v"(v[0]), "v"(v[1]), "v"(v[2]), "v"(v[3]));
        }
      }
    }
    __syncthreads();
  }

  // ---- cross-wave combine (reuse etile as Zbuf, qrel[0..255] as m/l) ----
#pragma unroll
  for (int dn = 0; dn < 4; ++dn)
    *reinterpret_cast<f32x4*>(&etile[(wid * 16 + l15) * 64 + dn * 16 + q4 * 4]) = zacc[dn];
  if (q4 == 0) {
    qrel[wid * 16 + l15] = mprev;
    qrel[128 + wid * 16 + l15] = lsum;
  }
  __syncthreads();

#pragma unroll
  for (int rr = 0; rr < 2; ++rr) {
    const int r = wid + rr * 8;
    float mf = -INFINITY;
#pragma unroll
    for (int w = 0; w < 8; ++w) mf = fmaxf(mf, qrel[w * 16 + r]);
    float lf = 0.f, z = 0.f;
#pragma unroll
    for (int w = 0; w < 8; ++w) {
      const float sc = __expf(qrel[w * 16 + r] - mf);
      lf += qrel[128 + w * 16 + r] * sc;
      z  += etile[(w * 16 + r) * 64 + lane] * sc;
    }
    Zout[((size_t)b * S_LEN + s0 + r) * DIM + lane] = z / lf;
  }
}

extern "C" void kernel_launch(void* const* d_in, const int* in_sizes, int n_in,
                              void* d_out, int out_size, void* d_ws, size_t ws_size,
                              hipStream_t stream) {
  const float* Q   = (const float*)d_in[0];
  const float* K   = (const float*)d_in[1];
  const float* V   = (const float*)d_in[2];
  const float* rel = (const float*)d_in[3];
  // d_in[4] = segment_ids (unused, segmented=False)

  const size_t kb_elems = (size_t)BATCH * KEXT * DIM;   // u16
  const size_t vt_elems = (size_t)BATCH * DIM * S_LEN;  // u16
  u16* Kb = (u16*)d_ws;
  u16* Vt = Kb + kb_elems;
  float* wsZ = (float*)(Vt + vt_elems);                  // 2 MB scratch Z for M1/M2
  float* wsE = wsZ + (size_t)BATCH * S_LEN * DIM;        // 134 MB linear energy for M2
  const size_t need_m2 =
      (char*)(wsE + (size_t)512 * 65536) - (char*)d_ws;

  float* energy = (float*)d_out;                          // [B][S][S]
  float* Zout   = energy + (size_t)BATCH * S_LEN * S_LEN; // [B][S][64]

  prep_k<<<dim3(KEXT / 4, BATCH), 256, 0, stream>>>(K, rel, Kb);
  prep_v<<<dim3(S_LEN / 64, BATCH), 256, 0, stream>>>(V, Vt);

  // Arm 1: no energy stores (compute-only floor)
  attn_main<1><<<dim3(BATCH * (S_LEN / 16)), 512, 0, stream>>>(Q, Kb, Vt, wsZ, wsZ);
  // Arm 2: linear-address stores, same volume (address-pattern probe)
  if (ws_size >= need_m2)
    attn_main<2><<<dim3(BATCH * (S_LEN / 16)), 512, 0, stream>>>(Q, Kb, Vt, wsE, wsZ);
  // Arm 0: real output (must be last; validates)
  attn_main<0><<<dim3(BATCH * (S_LEN / 16)), 512, 0, stream>>>(Q, Kb, Vt, energy, Zout);
}

// Round 7
// 80.040 us; speedup vs baseline: 2.7265x; 2.7265x over previous
//
#include <hip/hip_runtime.h>

#define S_LEN 4096
#define BATCH 2
#define DIM 64
#define RAD 128
#define NPOS 257
#define KEXT 4416              // 4096 + 5*64 (rel rows padded)
#define QREL_STR 260
#define PSTR 72                // P LDS row stride in u16 (144B, 16B-aligned)

typedef short s16x8 __attribute__((ext_vector_type(8)));
typedef short s16x4 __attribute__((ext_vector_type(4)));
typedef float f32x4 __attribute__((ext_vector_type(4)));
typedef unsigned short u16;
typedef unsigned int u32;

__device__ __forceinline__ u16 f2bf(float f) {
  union { float f; u32 u; } v; v.f = f;
  u32 u = v.u;
  return (u16)((u + 0x7FFFu + ((u >> 16) & 1u)) >> 16);  // RNE
}

// Kb_ext[b][t][d]: t<4096 -> bf16(K); 4096<=t<4353 -> bf16(rel[t-4096]); else 0
__global__ void prep_k(const float* __restrict__ K, const float* __restrict__ rel,
                       u16* __restrict__ Kb) {
  int b = blockIdx.y;
  int t = blockIdx.x * 4 + (threadIdx.x >> 6);
  int d = threadIdx.x & 63;
  float v = 0.f;
  if (t < S_LEN) v = K[((size_t)b * S_LEN + t) * DIM + d];
  else if (t - S_LEN < NPOS) v = rel[(size_t)(t - S_LEN) * DIM + d];
  Kb[((size_t)b * KEXT + t) * DIM + d] = f2bf(v);
}

// Vt[b][d][t] = bf16(V[b][t][d])
__global__ void prep_v(const float* __restrict__ V, u16* __restrict__ Vt) {
  __shared__ float tile[64][65];
  int b = blockIdx.y;
  int t0 = blockIdx.x * 64;
  for (int i = threadIdx.x; i < 4096; i += 256) {
    int tl = i >> 6, d = i & 63;
    tile[tl][d] = V[((size_t)b * S_LEN + t0 + tl) * DIM + d];
  }
  __syncthreads();
  for (int i = threadIdx.x; i < 4096; i += 256) {
    int d = i >> 6, tl = i & 63;
    Vt[((size_t)b * DIM + d) * S_LEN + t0 + tl] = f2bf(tile[tl][d]);
  }
}

// 16 q-rows per block, 4 waves (256 thr); wave w owns cols [w*1024,(w+1)*1024).
// NO barriers in the main loop (waves independent; stores direct from regs).
// Lean per-tile path: band-split rel (fma for ~91% of tiles), cvt_pk bf16
// packing, skip-rescale when the running max doesn't grow.
// Swapped-operand MFMAs keep q == l15 lane-local:
//   QK^T: mfma(kf, qf) -> D[t=q4*4+reg][q=l15]
//   PV:   mfma(vf, pf) -> D[d=dn*16+q4*4+reg][q=l15]
__launch_bounds__(256, 4)
__global__ void attn_main(const float* __restrict__ Q,
                          const u16* __restrict__ Kb,
                          const u16* __restrict__ Vt,
                          float* __restrict__ energy,
                          float* __restrict__ Zout) {
  __shared__ float smem[16 * QREL_STR];   // phase1: qrel[q=l15][p]; phase2: Zbuf[4][16][64]
  __shared__ float smem2[2304];           // phase1: P lds (4 waves x 16 x PSTR u16); phase2: m[64],l[64]

  const int tid = threadIdx.x;
  const int lane = tid & 63;
  const int wid = tid >> 6;
  const int l15 = lane & 15, q4 = lane >> 4;
  const int bx = blockIdx.x;
  const int b = bx >> 8;
  const int s0 = (bx & 255) * 16;

  const u16* KbB = Kb + (size_t)b * KEXT * DIM;
  const u16* VtB = Vt + (size_t)b * DIM * S_LEN;
  u16* plds = (u16*)smem2;

  // ---- Q B-fragments (row s0+l15) ----
  s16x8 qfrag[2];
  {
    const float* qp = Q + ((size_t)b * S_LEN + s0 + l15) * DIM + q4 * 8;
#pragma unroll
    for (int ks = 0; ks < 2; ++ks) {
      f32x4 a = *reinterpret_cast<const f32x4*>(qp + ks * 32);
      f32x4 c = *reinterpret_cast<const f32x4*>(qp + ks * 32 + 4);
      s16x8 f;
#pragma unroll
      for (int j = 0; j < 4; ++j) { f[j] = (short)f2bf(a[j]); f[4 + j] = (short)f2bf(c[j]); }
      qfrag[ks] = f;
    }
  }

  const int koff_lane = l15 * DIM + q4 * 8;

  // ---- prologue: Q_rel[p][q] via mfma(rel, q); wave w does chunks w, w+4 ----
  for (int pt = wid; pt < 5; pt += 4) {
    f32x4 acc[4] = {};
    const u16* kp = KbB + (size_t)(S_LEN + pt * 64) * DIM + koff_lane;
#pragma unroll
    for (int ks = 0; ks < 2; ++ks)
#pragma unroll
      for (int nf = 0; nf < 4; ++nf) {
        s16x8 kf = *reinterpret_cast<const s16x8*>(kp + nf * 16 * DIM + ks * 32);
        acc[nf] = __builtin_amdgcn_mfma_f32_16x16x32_bf16(kf, qfrag[ks], acc[nf], 0, 0, 0);
      }
#pragma unroll
    for (int nf = 0; nf < 4; ++nf)
#pragma unroll
      for (int reg = 0; reg < 4; ++reg) {
        int p = pt * 64 + nf * 16 + q4 * 4 + reg;
        if (p < NPOS) smem[l15 * QREL_STR + p] = acc[nf][reg];
      }
  }
  __syncthreads();

  // per-row clamped-rel constants, pre-scaled by 1/8
  const float c8lo = smem[l15 * QREL_STR + 0] * 0.125f;
  const float c8hi = smem[l15 * QREL_STR + 256] * 0.125f;

  // ---- main loop: 16 t-tiles of 64, per-wave, barrier-free ----
  const int qglob = s0 + l15;
  const int qoff = l15 * QREL_STR + RAD;
  u16* pw = plds + wid * 16 * PSTR;
  float* erow = energy + ((size_t)b * S_LEN + qglob) * S_LEN;

  float mprev = -INFINITY, lsum = 0.f;
  f32x4 zacc[4] = {};

  for (int it = 0; it < 16; ++it) {
    const int t0 = wid * 1024 + it * 64;

    // QK^T
    f32x4 acc[4] = {};
    const u16* kp = KbB + (size_t)t0 * DIM + koff_lane;
#pragma unroll
    for (int ks = 0; ks < 2; ++ks)
#pragma unroll
      for (int nf = 0; nf < 4; ++nf) {
        s16x8 kf = *reinterpret_cast<const s16x8*>(kp + nf * 16 * DIM + ks * 32);
        acc[nf] = __builtin_amdgcn_mfma_f32_16x16x32_bf16(kf, qfrag[ks], acc[nf], 0, 0, 0);
      }

    // V fragments issued early; latency hides under softmax
    s16x8 vf[2][4];
#pragma unroll
    for (int ks = 0; ks < 2; ++ks)
#pragma unroll
      for (int dn = 0; dn < 4; ++dn)
        vf[ks][dn] = *reinterpret_cast<const s16x8*>(
            VtB + (size_t)(dn * 16 + l15) * S_LEN + t0 + ks * 32 + q4 * 8);

    // rel shift + scale (band-split: fma for out-of-band tiles), lane max
    float mloc = -INFINITY;
    if (t0 >= s0 + 143) {
#pragma unroll
      for (int nf = 0; nf < 4; ++nf)
#pragma unroll
        for (int reg = 0; reg < 4; ++reg) {
          float e = fmaf(acc[nf][reg], 0.125f, c8hi);
          acc[nf][reg] = e;
          mloc = fmaxf(mloc, e);
        }
    } else if (t0 <= s0 - 191) {
#pragma unroll
      for (int nf = 0; nf < 4; ++nf)
#pragma unroll
        for (int reg = 0; reg < 4; ++reg) {
          float e = fmaf(acc[nf][reg], 0.125f, c8lo);
          acc[nf][reg] = e;
          mloc = fmaxf(mloc, e);
        }
    } else {
#pragma unroll
      for (int nf = 0; nf < 4; ++nf) {
        const int tb = t0 + nf * 16 + q4 * 4;
#pragma unroll
        for (int reg = 0; reg < 4; ++reg) {
          int p = tb + reg - qglob;
          p = (p < -RAD) ? -RAD : (p > RAD ? RAD : p);
          float e = (acc[nf][reg] + smem[qoff + p]) * 0.125f;
          acc[nf][reg] = e;
          mloc = fmaxf(mloc, e);
        }
      }
    }

    // energy store, direct from regs (proven: stores are not the bottleneck)
#pragma unroll
    for (int nf = 0; nf < 4; ++nf)
      __builtin_nontemporal_store(
          acc[nf], reinterpret_cast<f32x4*>(erow + t0 + nf * 16 + q4 * 4));

    // online softmax; skip rescale when max didn't grow (T13, THR=0)
    if (__all(mloc <= mprev)) {
      // keep mprev; zacc/lsum unchanged
    } else {
      mloc = fmaxf(mloc, __shfl_xor(mloc, 16));
      mloc = fmaxf(mloc, __shfl_xor(mloc, 32));
      const float mn = fmaxf(mprev, mloc);
      const float alpha = __expf(mprev - mn);
      mprev = mn;
      lsum *= alpha;
#pragma unroll
      for (int dn = 0; dn < 4; ++dn) zacc[dn] *= alpha;
    }

    float rs = 0.f;
#pragma unroll
    for (int nf = 0; nf < 4; ++nf) {
      float p0 = __expf(acc[nf][0] - mprev);
      float p1 = __expf(acc[nf][1] - mprev);
      float p2 = __expf(acc[nf][2] - mprev);
      float p3 = __expf(acc[nf][3] - mprev);
      rs += (p0 + p1) + (p2 + p3);
      union { u32 w[2]; s16x4 v; } pk;
      asm("v_cvt_pk_bf16_f32 %0, %1, %2" : "=v"(pk.w[0]) : "v"(p0), "v"(p1));
      asm("v_cvt_pk_bf16_f32 %0, %1, %2" : "=v"(pk.w[1]) : "v"(p2), "v"(p3));
      *reinterpret_cast<s16x4*>(pw + l15 * PSTR + nf * 16 + q4 * 4) = pk.v;
    }
    rs += __shfl_xor(rs, 16);
    rs += __shfl_xor(rs, 32);
    lsum += rs;

    // PV: mfma(vf, pf) -> zacc[dn] holds Z[d=dn*16+q4*4+reg][q=l15]
#pragma unroll
    for (int ks = 0; ks < 2; ++ks) {
      s16x8 pf = *reinterpret_cast<const s16x8*>(pw + l15 * PSTR + ks * 32 + q4 * 8);
#pragma unroll
      for (int dn = 0; dn < 4; ++dn)
        zacc[dn] = __builtin_amdgcn_mfma_f32_16x16x32_bf16(vf[ks][dn], pf, zacc[dn], 0, 0, 0);
    }
  }

  // ---- cross-wave combine (overlay: smem=Zbuf, smem2=m/l) ----
  __syncthreads();
#pragma unroll
  for (int dn = 0; dn < 4; ++dn)
    *reinterpret_cast<f32x4*>(&smem[(wid * 16 + l15) * 64 + dn * 16 + q4 * 4]) = zacc[dn];
  if (q4 == 0) {
    smem2[wid * 16 + l15] = mprev;
    smem2[64 + wid * 16 + l15] = lsum;
  }
  __syncthreads();

  {
    const int r0 = tid >> 6, d = tid & 63;
#pragma unroll
    for (int rr = 0; rr < 4; ++rr) {
      const int r = rr * 4 + r0;
      float mf = -INFINITY;
#pragma unroll
      for (int w = 0; w < 4; ++w) mf = fmaxf(mf, smem2[w * 16 + r]);
      float lf = 0.f, z = 0.f;
#pragma unroll
      for (int w = 0; w < 4; ++w) {
        const float sc = __expf(smem2[w * 16 + r] - mf);
        lf += smem2[64 + w * 16 + r] * sc;
        z  += smem[(w * 16 + r) * 64 + d] * sc;
      }
      Zout[((size_t)b * S_LEN + s0 + r) * DIM + d] = z / lf;
    }
  }
}

extern "C" void kernel_launch(void* const* d_in, const int* in_sizes, int n_in,
                              void* d_out, int out_size, void* d_ws, size_t ws_size,
                              hipStream_t stream) {
  const float* Q   = (const float*)d_in[0];
  const float* K   = (const float*)d_in[1];
  const float* V   = (const float*)d_in[2];
  const float* rel = (const float*)d_in[3];
  // d_in[4] = segment_ids (unused, segmented=False)

  u16* Kb = (u16*)d_ws;                                   // [B][KEXT][64] bf16
  u16* Vt = Kb + (size_t)BATCH * KEXT * DIM;              // [B][64][S] bf16

  float* energy = (float*)d_out;                          // [B][S][S]
  float* Zout   = energy + (size_t)BATCH * S_LEN * S_LEN; // [B][S][64]

  prep_k<<<dim3(KEXT / 4, BATCH), 256, 0, stream>>>(K, rel, Kb);
  prep_v<<<dim3(S_LEN / 64, BATCH), 256, 0, stream>>>(V, Vt);
  attn_main<<<dim3(BATCH * (S_LEN / 16)), 256, 0, stream>>>(Q, Kb, Vt, energy, Zout);
}